// Round 5
// baseline (628.177 us; speedup 1.0000x reference)
//
#include <hip/hip_runtime.h>
#include <hip/hip_bf16.h>
#include <math.h>

#define N_NODES 100000
#define N_EDGES 1600000
#define D_IN    256
#define D_OUT   128
#define NHEAD   4
#define CH      32
#define GN_EPS  1e-5f

typedef __attribute__((ext_vector_type(8))) short bf16x8;
typedef __attribute__((ext_vector_type(4))) float f32x4;

// ---------- small helpers ----------
__device__ inline float bf2f(unsigned short u) {
    return __uint_as_float(((unsigned int)u) << 16);
}
__device__ inline unsigned short f2bf(float f) {
    unsigned int x = __float_as_uint(f);
    unsigned int r = (x + 0x7fffu + ((x >> 16) & 1u)) >> 16;  // round-nearest-even
    return (unsigned short)r;
}
__device__ inline unsigned int pk2bf(float a, float b) {
    __hip_bfloat162 h = __float22bfloat162_rn(float2{a, b});
    return *(unsigned int*)&h;
}
__device__ inline float mishf(float x) {
    if (x > 15.0f) return x;
    float ex = __expf(x);
    float t = ex * (ex + 2.0f);
    return x * t / (t + 2.0f);
}

// ---------- kernel 0: build Wt (bf16, [512 cols][256 k]) + concat bias ----------
__global__ void prep_w(const float* __restrict__ Wq, const float* __restrict__ Wk,
                       const float* __restrict__ Wv, const float* __restrict__ Wsk,
                       const float* __restrict__ bq, const float* __restrict__ bk,
                       const float* __restrict__ bv, const float* __restrict__ bsk,
                       unsigned short* __restrict__ Wt, float* __restrict__ bcat) {
    int idx = blockIdx.x * 256 + threadIdx.x;   // 512 blocks * 256 = 131072
    int k = idx >> 9;
    int which = (idx >> 7) & 3;
    int c = idx & 127;
    const float* W = (which == 0) ? Wq : (which == 1) ? Wk : (which == 2) ? Wv : Wsk;
    int col = which * 128 + c;
    Wt[(size_t)col * 256 + k] = f2bf(W[(size_t)k * 128 + c]);
    if (idx < 512) {
        const float* b = (which == 0) ? bq : (which == 1) ? bk : (which == 2) ? bv : bsk;
        bcat[idx] = b[c];
    }
}

// ---------- kernel 1: fused 4x GEMM via bf16 MFMA ----------
// grid 1563, block 256 (4 waves). Block tile: 64 rows x 512 cols; wave w -> output w.
// Per wave: 4 sequential 16-row x 128-col ROW panels (acc[8] = 32 regs).
// Per ks-step: 1 a ds_read + 8 independent B loads hoisted (ILP) + 8 MFMA.
// Row-panel epilogue writes COMPLETE 128-col rows in one burst -> full-line HBM writes.
// x-tile in LDS with chunk16 XOR swizzle (c ^= row&7) -> conflict-free ds_read_b128.
__global__ __launch_bounds__(256, 3) void gemm_mfma(
    const float* __restrict__ x, const unsigned short* __restrict__ Wt,
    const float* __restrict__ bcat,
    unsigned short* __restrict__ qb, unsigned short* __restrict__ kb,
    unsigned short* __restrict__ vb, float* __restrict__ skip)
{
    __shared__ unsigned short xs[64 * 256];     // 32 KiB
    const int tid = threadIdx.x;
    const int nb = blockIdx.x * 64;

    // stage 64 rows (2048 chunks of 16 B), f32 -> bf16 packed, swizzled
    #pragma unroll
    for (int it = 0; it < 8; ++it) {
        int g = it * 256 + tid;
        int row = g >> 5, c = g & 31;
        int grow = nb + row;
        float4 v0 = make_float4(0.f, 0.f, 0.f, 0.f), v1 = v0;
        if (grow < N_NODES) {
            const float* xp = x + (size_t)grow * D_IN + c * 8;
            v0 = *(const float4*)xp;
            v1 = *(const float4*)(xp + 4);
        }
        int sc = c ^ (row & 7);
        uint4 w;
        w.x = pk2bf(v0.x, v0.y); w.y = pk2bf(v0.z, v0.w);
        w.z = pk2bf(v1.x, v1.y); w.w = pk2bf(v1.z, v1.w);
        *(uint4*)(xs + row * 256 + sc * 8) = w;
    }
    __syncthreads();

    const int wave = tid >> 6, lane = tid & 63;
    const int lm = lane & 15, lk = lane >> 4;
    const unsigned short* wb = Wt + (size_t)wave * 128 * 256;
    unsigned short* dstb = (wave == 0) ? qb : (wave == 1) ? kb : vb;

    #pragma unroll
    for (int rp = 0; rp < 4; ++rp) {
        f32x4 acc[8] = {};

        #pragma unroll
        for (int ks = 0; ks < 8; ++ks) {
            // 8 independent B loads (L2-resident Wt) — issued together for ILP
            bf16x8 b[8];
            const int k0 = ks * 32 + lk * 8;
            #pragma unroll
            for (int cf = 0; cf < 8; ++cf)
                b[cf] = *(const bf16x8*)(wb + (size_t)(cf * 16 + lm) * 256 + k0);

            // A fragment: row rp*16+lm, swizzled chunk
            int c = (ks * 4 + lk) ^ (lm & 7);
            bf16x8 a = *(const bf16x8*)(xs + (rp * 16 + lm) * 256 + c * 8);

            #pragma unroll
            for (int cf = 0; cf < 8; ++cf)
                acc[cf] = __builtin_amdgcn_mfma_f32_16x16x32_bf16(a, b[cf], acc[cf], 0, 0, 0);
        }

        // epilogue: rows nb + rp*16 + lk*4 + j, cols cf*16+lm (all 128 cols per row)
        #pragma unroll
        for (int j = 0; j < 4; ++j) {
            const int r = nb + rp * 16 + lk * 4 + j;
            if (r < N_NODES) {
                if (wave == 3) {
                    #pragma unroll
                    for (int cf = 0; cf < 8; ++cf) {
                        const int col = cf * 16 + lm;
                        skip[(size_t)r * D_OUT + col] = acc[cf][j] + bcat[384 + col];
                    }
                } else {
                    #pragma unroll
                    for (int cf = 0; cf < 8; ++cf) {
                        const int col = cf * 16 + lm;
                        dstb[(size_t)r * D_OUT + col] = f2bf(acc[cf][j] + bcat[wave * 128 + col]);
                    }
                }
            }
        }
    }
}

// ---------- kernel 2: degree histogram ----------
__global__ void hist_kernel(const int* __restrict__ dst, int* __restrict__ deg) {
    int e = blockIdx.x * 256 + threadIdx.x;
    if (e < N_EDGES) atomicAdd(&deg[dst[e]], 1);
}

// ---------- kernels 3-5: exclusive scan of deg -> off (2-level) ----------
__global__ __launch_bounds__(256) void scan1(const int* __restrict__ deg,
                                             int* __restrict__ off,
                                             int* __restrict__ bsum) {
    __shared__ int lds[256];
    int t = threadIdx.x;
    int base = blockIdx.x * 1024 + t * 4;
    int d0 = 0, d1 = 0, d2 = 0, d3 = 0;
    if (base + 3 < N_NODES) {
        int4 dd = *(const int4*)(deg + base);
        d0 = dd.x; d1 = dd.y; d2 = dd.z; d3 = dd.w;
    } else {
        if (base     < N_NODES) d0 = deg[base];
        if (base + 1 < N_NODES) d1 = deg[base + 1];
        if (base + 2 < N_NODES) d2 = deg[base + 2];
        if (base + 3 < N_NODES) d3 = deg[base + 3];
    }
    int s = d0 + d1 + d2 + d3;
    lds[t] = s;
    __syncthreads();
    for (int d = 1; d < 256; d <<= 1) {
        int u = (t >= d) ? lds[t - d] : 0;
        __syncthreads();
        lds[t] += u;
        __syncthreads();
    }
    int excl = lds[t] - s;
    if (base     < N_NODES) off[base]     = excl;
    if (base + 1 < N_NODES) off[base + 1] = excl + d0;
    if (base + 2 < N_NODES) off[base + 2] = excl + d0 + d1;
    if (base + 3 < N_NODES) off[base + 3] = excl + d0 + d1 + d2;
    if (t == 255) bsum[blockIdx.x] = lds[255];
}

__global__ void scan2(int* __restrict__ bsum) {  // 1 block, 128 threads, 98 values
    __shared__ int lds[128];
    int t = threadIdx.x;
    int v = (t < 98) ? bsum[t] : 0;
    lds[t] = v;
    __syncthreads();
    for (int d = 1; d < 128; d <<= 1) {
        int u = (t >= d) ? lds[t - d] : 0;
        __syncthreads();
        lds[t] += u;
        __syncthreads();
    }
    if (t < 98) bsum[t] = lds[t] - v;  // exclusive
}

__global__ void scan3(int* __restrict__ off, int* __restrict__ cursor,
                      const int* __restrict__ bsum) {
    int add = bsum[blockIdx.x];
    int base = blockIdx.x * 1024 + threadIdx.x * 4;
    #pragma unroll
    for (int j = 0; j < 4; ++j) {
        int idx = base + j;
        if (idx < N_NODES) {
            int vv = off[idx] + add;
            off[idx] = vv;
            cursor[idx] = vv;
        }
    }
}

// ---------- kernel 6: scatter edges into dst-sorted order ----------
__global__ void scatter_kernel(const int* __restrict__ src, const int* __restrict__ dst,
                               int* __restrict__ cursor, int* __restrict__ ssrc) {
    int e = blockIdx.x * 256 + threadIdx.x;
    if (e < N_EDGES) {
        int d = dst[e];
        int p = atomicAdd(&cursor[d], 1);
        ssrc[p] = src[e];
    }
}

// ---------- kernel 7: per-node attention, single-pass online softmax ----------
// block = 256 = 4 waves; one wave per destination node.
// lane -> channels c0=2*lane, c0+1 ; head = lane>>4 (16 lanes per head).
__global__ __launch_bounds__(256) void aggregate(
    const unsigned short* __restrict__ qb, const unsigned short* __restrict__ kb,
    const unsigned short* __restrict__ vb,
    const int* __restrict__ off, const int* __restrict__ endp,
    const int* __restrict__ ssrc, float* __restrict__ out)
{
    const int wave = threadIdx.x >> 6;
    const int lane = threadIdx.x & 63;
    const int n = blockIdx.x * 4 + wave;
    const int c0 = lane * 2;
    const float scale = 0.17677669529663687f;  // 1/sqrt(32)

    unsigned int qv = *(const unsigned int*)(qb + (size_t)n * D_OUT + c0);
    float q0 = bf2f((unsigned short)(qv & 0xffffu));
    float q1 = bf2f((unsigned short)(qv >> 16));

    const int s0 = off[n], s1 = endp[n];

    float m = -1e30f, den = 0.f, a0 = 0.f, a1 = 0.f;

    int i = s0;
    for (; i + 4 <= s1; i += 4) {
        int sA = ssrc[i], sB = ssrc[i + 1], sC = ssrc[i + 2], sD = ssrc[i + 3];
        unsigned int kA = *(const unsigned int*)(kb + (size_t)sA * D_OUT + c0);
        unsigned int kB = *(const unsigned int*)(kb + (size_t)sB * D_OUT + c0);
        unsigned int kC = *(const unsigned int*)(kb + (size_t)sC * D_OUT + c0);
        unsigned int kD = *(const unsigned int*)(kb + (size_t)sD * D_OUT + c0);
        unsigned int vA = *(const unsigned int*)(vb + (size_t)sA * D_OUT + c0);
        unsigned int vB = *(const unsigned int*)(vb + (size_t)sB * D_OUT + c0);
        unsigned int vC = *(const unsigned int*)(vb + (size_t)sC * D_OUT + c0);
        unsigned int vD = *(const unsigned int*)(vb + (size_t)sD * D_OUT + c0);

        float pA = q0 * bf2f((unsigned short)(kA & 0xffffu)) + q1 * bf2f((unsigned short)(kA >> 16));
        float pB = q0 * bf2f((unsigned short)(kB & 0xffffu)) + q1 * bf2f((unsigned short)(kB >> 16));
        float pC = q0 * bf2f((unsigned short)(kC & 0xffffu)) + q1 * bf2f((unsigned short)(kC >> 16));
        float pD = q0 * bf2f((unsigned short)(kD & 0xffffu)) + q1 * bf2f((unsigned short)(kD >> 16));
        pA += __shfl_xor(pA, 1); pB += __shfl_xor(pB, 1); pC += __shfl_xor(pC, 1); pD += __shfl_xor(pD, 1);
        pA += __shfl_xor(pA, 2); pB += __shfl_xor(pB, 2); pC += __shfl_xor(pC, 2); pD += __shfl_xor(pD, 2);
        pA += __shfl_xor(pA, 4); pB += __shfl_xor(pB, 4); pC += __shfl_xor(pC, 4); pD += __shfl_xor(pD, 4);
        pA += __shfl_xor(pA, 8); pB += __shfl_xor(pB, 8); pC += __shfl_xor(pC, 8); pD += __shfl_xor(pD, 8);
        pA *= scale; pB *= scale; pC *= scale; pD *= scale;

        float newm = fmaxf(m, fmaxf(fmaxf(pA, pB), fmaxf(pC, pD)));
        float corr = __expf(m - newm);
        float wA = __expf(pA - newm), wB = __expf(pB - newm);
        float wC = __expf(pC - newm), wD = __expf(pD - newm);
        den = den * corr + ((wA + wB) + (wC + wD));
        a0 = a0 * corr + wA * bf2f((unsigned short)(vA & 0xffffu))
                       + wB * bf2f((unsigned short)(vB & 0xffffu))
                       + wC * bf2f((unsigned short)(vC & 0xffffu))
                       + wD * bf2f((unsigned short)(vD & 0xffffu));
        a1 = a1 * corr + wA * bf2f((unsigned short)(vA >> 16))
                       + wB * bf2f((unsigned short)(vB >> 16))
                       + wC * bf2f((unsigned short)(vC >> 16))
                       + wD * bf2f((unsigned short)(vD >> 16));
        m = newm;
    }
    for (; i < s1; ++i) {
        int s = ssrc[i];
        unsigned int kv = *(const unsigned int*)(kb + (size_t)s * D_OUT + c0);
        unsigned int vv = *(const unsigned int*)(vb + (size_t)s * D_OUT + c0);
        float p = q0 * bf2f((unsigned short)(kv & 0xffffu)) + q1 * bf2f((unsigned short)(kv >> 16));
        p += __shfl_xor(p, 1);
        p += __shfl_xor(p, 2);
        p += __shfl_xor(p, 4);
        p += __shfl_xor(p, 8);
        p *= scale;
        float newm = fmaxf(m, p);
        float corr = __expf(m - newm);
        float w = __expf(p - newm);
        den = den * corr + w;
        a0 = a0 * corr + w * bf2f((unsigned short)(vv & 0xffffu));
        a1 = a1 * corr + w * bf2f((unsigned short)(vv >> 16));
        m = newm;
    }

    float invd = (den > 0.f) ? 1.0f / den : 0.f;
    size_t o = (size_t)n * D_OUT + c0;
    float2 sk = *(float2*)(out + o);
    sk.x += a0 * invd;
    sk.y += a1 * invd;
    *(float2*)(out + o) = sk;
}

// ---------- kernel 8: per-channel sum / sumsq ----------
__global__ __launch_bounds__(256) void norm_reduce(const float* __restrict__ out,
                                                   float* __restrict__ sums) {
    const int total = N_NODES * D_OUT;
    const int stride = gridDim.x * 256;           // multiple of 128
    int t = threadIdx.x;
    float s = 0.f, s2 = 0.f;
    for (int i = blockIdx.x * 256 + t; i < total; i += stride) {
        float v = out[i];
        s += v; s2 += v * v;
    }
    __shared__ float ls[256], lq[256];
    ls[t] = s; lq[t] = s2;
    __syncthreads();
    if (t < 128) {
        s  = ls[t] + ls[t + 128];
        s2 = lq[t] + lq[t + 128];
        atomicAdd(&sums[t], s);
        atomicAdd(&sums[128 + t], s2);
    }
}

// ---------- kernel 9: finalize affine coefficients ----------
__global__ void finalize(const float* __restrict__ sums, const float* __restrict__ gw,
                         const float* __restrict__ gb, const float* __restrict__ gms,
                         float* __restrict__ AB) {
    int c = threadIdx.x;  // 128 threads
    const float invN = 1.0f / (float)N_NODES;
    float mean = sums[c] * invN;
    float ex2  = sums[128 + c] * invN;
    float mu = mean * gms[c];
    float var = ex2 - 2.f * mu * mean + mu * mu;
    float inv = rsqrtf(var + GN_EPS);
    float A = gw[c] * inv;
    AB[c] = A;
    AB[128 + c] = gb[c] - mu * A;
}

// ---------- kernel 10: affine + mish (in place on d_out) ----------
__global__ __launch_bounds__(256) void mish_kernel(float* __restrict__ out,
                                                   const float* __restrict__ AB) {
    int i = blockIdx.x * 256 + threadIdx.x;       // one float4 each; grid exact
    int c4 = (i << 2) & 127;
    float4 a  = *(const float4*)(AB + c4);
    float4 b  = *(const float4*)(AB + 128 + c4);
    float4 v  = *(float4*)(out + (size_t)i * 4);
    v.x = mishf(a.x * v.x + b.x);
    v.y = mishf(a.y * v.y + b.y);
    v.z = mishf(a.z * v.z + b.z);
    v.w = mishf(a.w * v.w + b.w);
    *(float4*)(out + (size_t)i * 4) = v;
}

// ---------- launch ----------
extern "C" void kernel_launch(void* const* d_in, const int* in_sizes, int n_in,
                              void* d_out, int out_size, void* d_ws, size_t ws_size,
                              hipStream_t stream) {
    (void)in_sizes; (void)n_in; (void)out_size; (void)ws_size;

    const float* x    = (const float*)d_in[0];
    const int*   ei   = (const int*)d_in[1];
    const float* Wq   = (const float*)d_in[2];
    const float* bq   = (const float*)d_in[3];
    const float* Wk   = (const float*)d_in[4];
    const float* bk   = (const float*)d_in[5];
    const float* Wv   = (const float*)d_in[6];
    const float* bv   = (const float*)d_in[7];
    const float* Wsk  = (const float*)d_in[8];
    const float* bsk  = (const float*)d_in[9];
    const float* gw   = (const float*)d_in[10];
    const float* gb   = (const float*)d_in[11];
    const float* gms  = (const float*)d_in[12];
    float* out = (float*)d_out;

    char* ws = (char*)d_ws;
    size_t o = 0;
    auto alloc = [&](size_t bytes) -> char* {
        char* p = ws + o;
        o += (bytes + 255) & ~(size_t)255;
        return p;
    };

    unsigned short* qb = (unsigned short*)alloc((size_t)N_NODES * D_OUT * 2);
    unsigned short* kb = (unsigned short*)alloc((size_t)N_NODES * D_OUT * 2);
    unsigned short* vb = (unsigned short*)alloc((size_t)N_NODES * D_OUT * 2);
    int* ssrc     = (int*)alloc((size_t)N_EDGES * 4);
    int* deg      = (int*)alloc((size_t)N_NODES * 4);
    int* off      = (int*)alloc((size_t)(N_NODES + 1) * 4);
    int* cursor   = (int*)alloc((size_t)N_NODES * 4);
    int* bsum     = (int*)alloc(512);
    float* sums   = (float*)alloc(1024);
    float* AB     = (float*)alloc(1024);
    unsigned short* Wt = (unsigned short*)alloc((size_t)512 * 256 * 2);
    float* bcat   = (float*)alloc(512 * 4);

    const int* srcp = ei;
    const int* dstp = ei + N_EDGES;

    hipMemsetAsync(deg, 0, (size_t)N_NODES * 4, stream);
    hipMemsetAsync(sums, 0, 256 * 4, stream);

    prep_w<<<512, 256, 0, stream>>>(Wq, Wk, Wv, Wsk, bq, bk, bv, bsk, Wt, bcat);
    gemm_mfma<<<(N_NODES + 63) / 64, 256, 0, stream>>>(x, Wt, bcat, qb, kb, vb, out);

    hist_kernel<<<(N_EDGES + 255) / 256, 256, 0, stream>>>(dstp, deg);
    scan1<<<98, 256, 0, stream>>>(deg, off, bsum);
    scan2<<<1, 128, 0, stream>>>(bsum);
    scan3<<<98, 256, 0, stream>>>(off, cursor, bsum);
    scatter_kernel<<<(N_EDGES + 255) / 256, 256, 0, stream>>>(srcp, dstp, cursor, ssrc);

    aggregate<<<N_NODES / 4, 256, 0, stream>>>(qb, kb, vb, off, cursor, ssrc, out);

    norm_reduce<<<512, 256, 0, stream>>>(out, sums);
    finalize<<<1, 128, 0, stream>>>(sums, gw, gb, gms, AB);
    mish_kernel<<<(N_NODES * D_OUT / 4) / 256, 256, 0, stream>>>(out, AB);
}

// Round 6
// 509.558 us; speedup vs baseline: 1.2328x; 1.2328x over previous
//
#include <hip/hip_runtime.h>
#include <hip/hip_bf16.h>
#include <math.h>

#define N_NODES 100000
#define N_EDGES 1600000
#define D_IN    256
#define D_OUT   128
#define NHEAD   4
#define CH      32
#define GN_EPS  1e-5f

typedef __attribute__((ext_vector_type(8))) short bf16x8;
typedef __attribute__((ext_vector_type(4))) float f32x4;

// ---------- small helpers ----------
__device__ inline float bf2f(unsigned short u) {
    return __uint_as_float(((unsigned int)u) << 16);
}
__device__ inline unsigned short f2bf(float f) {
    unsigned int x = __float_as_uint(f);
    unsigned int r = (x + 0x7fffu + ((x >> 16) & 1u)) >> 16;  // round-nearest-even
    return (unsigned short)r;
}
__device__ inline unsigned int pk2bf(float a, float b) {
    __hip_bfloat162 h = __float22bfloat162_rn(float2{a, b});
    return *(unsigned int*)&h;
}
__device__ inline float mishf(float x) {
    if (x > 15.0f) return x;
    float ex = __expf(x);
    float t = ex * (ex + 2.0f);
    return x * t / (t + 2.0f);
}

// ---------- kernel 0: build Wt (bf16, [512 cols][256 k]) + concat bias ----------
__global__ void prep_w(const float* __restrict__ Wq, const float* __restrict__ Wk,
                       const float* __restrict__ Wv, const float* __restrict__ Wsk,
                       const float* __restrict__ bq, const float* __restrict__ bk,
                       const float* __restrict__ bv, const float* __restrict__ bsk,
                       unsigned short* __restrict__ Wt, float* __restrict__ bcat) {
    int idx = blockIdx.x * 256 + threadIdx.x;   // 512 blocks * 256 = 131072
    int k = idx >> 9;
    int which = (idx >> 7) & 3;
    int c = idx & 127;
    const float* W = (which == 0) ? Wq : (which == 1) ? Wk : (which == 2) ? Wv : Wsk;
    int col = which * 128 + c;
    Wt[(size_t)col * 256 + k] = f2bf(W[(size_t)k * 128 + c]);
    if (idx < 512) {
        const float* b = (which == 0) ? bq : (which == 1) ? bk : (which == 2) ? bv : bsk;
        bcat[idx] = b[c];
    }
}

// ---------- kernel 1: fused 4x GEMM via bf16 MFMA, both operands through LDS ----
// grid 1563, block 512 (8 waves). Block tile: 64 rows x 512 cols (all 4 matrices).
// BK=64, 4 k-steps, 2-barrier loop. Wave (wr,wc)=(w>>2,w&3) -> 32x128 of matrix wc
// (acc[2][8] = 64 regs, whole wave writes one matrix -> no divergence, full rows).
// x read ONCE from HBM (f32->bf16 in staging). LDS chunk-XOR swizzle on A and B
// (chunk c stored at c^(row&7)) -> lm-lanes span all 8 bank groups on ds_read_b128.
__global__ __launch_bounds__(512, 4) void gemm_mfma(
    const float* __restrict__ x, const unsigned short* __restrict__ Wt,
    const float* __restrict__ bcat,
    unsigned short* __restrict__ qb, unsigned short* __restrict__ kb,
    unsigned short* __restrict__ vb, float* __restrict__ skip)
{
    __shared__ unsigned short as_[64 * 64];     // 8 KiB  (64 rows x 64 k)
    __shared__ unsigned short bs_[512 * 64];    // 64 KiB (512 cols x 64 k)
    const int tid = threadIdx.x;
    const int nb = blockIdx.x * 64;

    const int wave = tid >> 6, lane = tid & 63;
    const int lm = lane & 15, lk = lane >> 4;
    const int wr = wave >> 2, wc = wave & 3;    // wr: row half, wc: matrix

    f32x4 acc[2][8] = {};

    for (int ks = 0; ks < 4; ++ks) {
        // ---- stage A: 64 rows x 64 k, f32 -> bf16, swizzled (1 chunk/thread) ----
        {
            int row = tid >> 3, c = tid & 7;
            int grow = nb + row;
            float4 v0 = make_float4(0.f, 0.f, 0.f, 0.f), v1 = v0;
            if (grow < N_NODES) {
                const float* xp = x + (size_t)grow * D_IN + ks * 64 + c * 8;
                v0 = *(const float4*)xp;
                v1 = *(const float4*)(xp + 4);
            }
            uint4 w;
            w.x = pk2bf(v0.x, v0.y); w.y = pk2bf(v0.z, v0.w);
            w.z = pk2bf(v1.x, v1.y); w.w = pk2bf(v1.z, v1.w);
            *(uint4*)(as_ + row * 64 + (c ^ (row & 7)) * 8) = w;
        }
        // ---- stage B: 512 cols x 64 k bf16 from Wt (8 chunks/thread) ----
        #pragma unroll
        for (int it = 0; it < 8; ++it) {
            int g = it * 512 + tid;             // 0..4095
            int col = g >> 3, c = g & 7;
            uint4 v = *(const uint4*)(Wt + (size_t)col * 256 + ks * 64 + c * 8);
            *(uint4*)(bs_ + col * 64 + (c ^ (col & 7)) * 8) = v;
        }
        __syncthreads();

        // ---- compute: 2 inner k-chunks of 32 ----
        #pragma unroll
        for (int inner = 0; inner < 2; ++inner) {
            const int ch = inner * 4 + lk;
            bf16x8 a[2], b[8];
            #pragma unroll
            for (int rf = 0; rf < 2; ++rf) {
                int row = wr * 32 + rf * 16 + lm;
                a[rf] = *(const bf16x8*)(as_ + row * 64 + (ch ^ (row & 7)) * 8);
            }
            #pragma unroll
            for (int cf = 0; cf < 8; ++cf) {
                int bcol = wc * 128 + cf * 16 + lm;
                b[cf] = *(const bf16x8*)(bs_ + bcol * 64 + (ch ^ (bcol & 7)) * 8);
            }
            #pragma unroll
            for (int cf = 0; cf < 8; ++cf) {
                acc[0][cf] = __builtin_amdgcn_mfma_f32_16x16x32_bf16(a[0], b[cf], acc[0][cf], 0, 0, 0);
                acc[1][cf] = __builtin_amdgcn_mfma_f32_16x16x32_bf16(a[1], b[cf], acc[1][cf], 0, 0, 0);
            }
        }
        __syncthreads();
    }

    // ---- epilogue: C/D layout col=lane&15, row=(lane>>4)*4+j ----
    unsigned short* dstb = (wc == 0) ? qb : (wc == 1) ? kb : vb;
    const float* biasp = bcat + wc * 128;
    #pragma unroll
    for (int rf = 0; rf < 2; ++rf) {
        #pragma unroll
        for (int j = 0; j < 4; ++j) {
            const int r = nb + wr * 32 + rf * 16 + lk * 4 + j;
            if (r < N_NODES) {
                if (wc == 3) {
                    #pragma unroll
                    for (int cf = 0; cf < 8; ++cf) {
                        const int col = cf * 16 + lm;
                        skip[(size_t)r * D_OUT + col] = acc[rf][cf][j] + biasp[col];
                    }
                } else {
                    #pragma unroll
                    for (int cf = 0; cf < 8; ++cf) {
                        const int col = cf * 16 + lm;
                        dstb[(size_t)r * D_OUT + col] = f2bf(acc[rf][cf][j] + biasp[col]);
                    }
                }
            }
        }
    }
}

// ---------- kernel 2: degree histogram ----------
__global__ void hist_kernel(const int* __restrict__ dst, int* __restrict__ deg) {
    int e = blockIdx.x * 256 + threadIdx.x;
    if (e < N_EDGES) atomicAdd(&deg[dst[e]], 1);
}

// ---------- kernels 3-5: exclusive scan of deg -> off (2-level) ----------
__global__ __launch_bounds__(256) void scan1(const int* __restrict__ deg,
                                             int* __restrict__ off,
                                             int* __restrict__ bsum) {
    __shared__ int lds[256];
    int t = threadIdx.x;
    int base = blockIdx.x * 1024 + t * 4;
    int d0 = 0, d1 = 0, d2 = 0, d3 = 0;
    if (base + 3 < N_NODES) {
        int4 dd = *(const int4*)(deg + base);
        d0 = dd.x; d1 = dd.y; d2 = dd.z; d3 = dd.w;
    } else {
        if (base     < N_NODES) d0 = deg[base];
        if (base + 1 < N_NODES) d1 = deg[base + 1];
        if (base + 2 < N_NODES) d2 = deg[base + 2];
        if (base + 3 < N_NODES) d3 = deg[base + 3];
    }
    int s = d0 + d1 + d2 + d3;
    lds[t] = s;
    __syncthreads();
    for (int d = 1; d < 256; d <<= 1) {
        int u = (t >= d) ? lds[t - d] : 0;
        __syncthreads();
        lds[t] += u;
        __syncthreads();
    }
    int excl = lds[t] - s;
    if (base     < N_NODES) off[base]     = excl;
    if (base + 1 < N_NODES) off[base + 1] = excl + d0;
    if (base + 2 < N_NODES) off[base + 2] = excl + d0 + d1;
    if (base + 3 < N_NODES) off[base + 3] = excl + d0 + d1 + d2;
    if (t == 255) bsum[blockIdx.x] = lds[255];
}

__global__ void scan2(int* __restrict__ bsum) {  // 1 block, 128 threads, 98 values
    __shared__ int lds[128];
    int t = threadIdx.x;
    int v = (t < 98) ? bsum[t] : 0;
    lds[t] = v;
    __syncthreads();
    for (int d = 1; d < 128; d <<= 1) {
        int u = (t >= d) ? lds[t - d] : 0;
        __syncthreads();
        lds[t] += u;
        __syncthreads();
    }
    if (t < 98) bsum[t] = lds[t] - v;  // exclusive
}

__global__ void scan3(int* __restrict__ off, int* __restrict__ cursor,
                      const int* __restrict__ bsum) {
    int add = bsum[blockIdx.x];
    int base = blockIdx.x * 1024 + threadIdx.x * 4;
    #pragma unroll
    for (int j = 0; j < 4; ++j) {
        int idx = base + j;
        if (idx < N_NODES) {
            int vv = off[idx] + add;
            off[idx] = vv;
            cursor[idx] = vv;
        }
    }
}

// ---------- kernel 6: scatter edges into dst-sorted order ----------
__global__ void scatter_kernel(const int* __restrict__ src, const int* __restrict__ dst,
                               int* __restrict__ cursor, int* __restrict__ ssrc) {
    int e = blockIdx.x * 256 + threadIdx.x;
    if (e < N_EDGES) {
        int d = dst[e];
        int p = atomicAdd(&cursor[d], 1);
        ssrc[p] = src[e];
    }
}

// ---------- kernel 7: per-node attention, single-pass online softmax ----------
// block = 256 = 4 waves; one wave per destination node.
// lane -> channels c0=2*lane, c0+1 ; head = lane>>4 (16 lanes per head).
__global__ __launch_bounds__(256) void aggregate(
    const unsigned short* __restrict__ qb, const unsigned short* __restrict__ kb,
    const unsigned short* __restrict__ vb,
    const int* __restrict__ off, const int* __restrict__ endp,
    const int* __restrict__ ssrc, float* __restrict__ out)
{
    const int wave = threadIdx.x >> 6;
    const int lane = threadIdx.x & 63;
    const int n = blockIdx.x * 4 + wave;
    const int c0 = lane * 2;
    const float scale = 0.17677669529663687f;  // 1/sqrt(32)

    unsigned int qv = *(const unsigned int*)(qb + (size_t)n * D_OUT + c0);
    float q0 = bf2f((unsigned short)(qv & 0xffffu));
    float q1 = bf2f((unsigned short)(qv >> 16));

    const int s0 = off[n], s1 = endp[n];

    float m = -1e30f, den = 0.f, a0 = 0.f, a1 = 0.f;

    int i = s0;
    for (; i + 4 <= s1; i += 4) {
        int sA = ssrc[i], sB = ssrc[i + 1], sC = ssrc[i + 2], sD = ssrc[i + 3];
        unsigned int kA = *(const unsigned int*)(kb + (size_t)sA * D_OUT + c0);
        unsigned int kB = *(const unsigned int*)(kb + (size_t)sB * D_OUT + c0);
        unsigned int kC = *(const unsigned int*)(kb + (size_t)sC * D_OUT + c0);
        unsigned int kD = *(const unsigned int*)(kb + (size_t)sD * D_OUT + c0);
        unsigned int vA = *(const unsigned int*)(vb + (size_t)sA * D_OUT + c0);
        unsigned int vB = *(const unsigned int*)(vb + (size_t)sB * D_OUT + c0);
        unsigned int vC = *(const unsigned int*)(vb + (size_t)sC * D_OUT + c0);
        unsigned int vD = *(const unsigned int*)(vb + (size_t)sD * D_OUT + c0);

        float pA = q0 * bf2f((unsigned short)(kA & 0xffffu)) + q1 * bf2f((unsigned short)(kA >> 16));
        float pB = q0 * bf2f((unsigned short)(kB & 0xffffu)) + q1 * bf2f((unsigned short)(kB >> 16));
        float pC = q0 * bf2f((unsigned short)(kC & 0xffffu)) + q1 * bf2f((unsigned short)(kC >> 16));
        float pD = q0 * bf2f((unsigned short)(kD & 0xffffu)) + q1 * bf2f((unsigned short)(kD >> 16));
        pA += __shfl_xor(pA, 1); pB += __shfl_xor(pB, 1); pC += __shfl_xor(pC, 1); pD += __shfl_xor(pD, 1);
        pA += __shfl_xor(pA, 2); pB += __shfl_xor(pB, 2); pC += __shfl_xor(pC, 2); pD += __shfl_xor(pD, 2);
        pA += __shfl_xor(pA, 4); pB += __shfl_xor(pB, 4); pC += __shfl_xor(pC, 4); pD += __shfl_xor(pD, 4);
        pA += __shfl_xor(pA, 8); pB += __shfl_xor(pB, 8); pC += __shfl_xor(pC, 8); pD += __shfl_xor(pD, 8);
        pA *= scale; pB *= scale; pC *= scale; pD *= scale;

        float newm = fmaxf(m, fmaxf(fmaxf(pA, pB), fmaxf(pC, pD)));
        float corr = __expf(m - newm);
        float wA = __expf(pA - newm), wB = __expf(pB - newm);
        float wC = __expf(pC - newm), wD = __expf(pD - newm);
        den = den * corr + ((wA + wB) + (wC + wD));
        a0 = a0 * corr + wA * bf2f((unsigned short)(vA & 0xffffu))
                       + wB * bf2f((unsigned short)(vB & 0xffffu))
                       + wC * bf2f((unsigned short)(vC & 0xffffu))
                       + wD * bf2f((unsigned short)(vD & 0xffffu));
        a1 = a1 * corr + wA * bf2f((unsigned short)(vA >> 16))
                       + wB * bf2f((unsigned short)(vB >> 16))
                       + wC * bf2f((unsigned short)(vC >> 16))
                       + wD * bf2f((unsigned short)(vD >> 16));
        m = newm;
    }
    for (; i < s1; ++i) {
        int s = ssrc[i];
        unsigned int kv = *(const unsigned int*)(kb + (size_t)s * D_OUT + c0);
        unsigned int vv = *(const unsigned int*)(vb + (size_t)s * D_OUT + c0);
        float p = q0 * bf2f((unsigned short)(kv & 0xffffu)) + q1 * bf2f((unsigned short)(kv >> 16));
        p += __shfl_xor(p, 1);
        p += __shfl_xor(p, 2);
        p += __shfl_xor(p, 4);
        p += __shfl_xor(p, 8);
        p *= scale;
        float newm = fmaxf(m, p);
        float corr = __expf(m - newm);
        float w = __expf(p - newm);
        den = den * corr + w;
        a0 = a0 * corr + w * bf2f((unsigned short)(vv & 0xffffu));
        a1 = a1 * corr + w * bf2f((unsigned short)(vv >> 16));
        m = newm;
    }

    float invd = (den > 0.f) ? 1.0f / den : 0.f;
    size_t o = (size_t)n * D_OUT + c0;
    float2 sk = *(float2*)(out + o);
    sk.x += a0 * invd;
    sk.y += a1 * invd;
    *(float2*)(out + o) = sk;
}

// ---------- kernel 8: per-channel sum / sumsq ----------
__global__ __launch_bounds__(256) void norm_reduce(const float* __restrict__ out,
                                                   float* __restrict__ sums) {
    const int total = N_NODES * D_OUT;
    const int stride = gridDim.x * 256;           // multiple of 128
    int t = threadIdx.x;
    float s = 0.f, s2 = 0.f;
    for (int i = blockIdx.x * 256 + t; i < total; i += stride) {
        float v = out[i];
        s += v; s2 += v * v;
    }
    __shared__ float ls[256], lq[256];
    ls[t] = s; lq[t] = s2;
    __syncthreads();
    if (t < 128) {
        s  = ls[t] + ls[t + 128];
        s2 = lq[t] + lq[t + 128];
        atomicAdd(&sums[t], s);
        atomicAdd(&sums[128 + t], s2);
    }
}

// ---------- kernel 9: finalize affine coefficients ----------
__global__ void finalize(const float* __restrict__ sums, const float* __restrict__ gw,
                         const float* __restrict__ gb, const float* __restrict__ gms,
                         float* __restrict__ AB) {
    int c = threadIdx.x;  // 128 threads
    const float invN = 1.0f / (float)N_NODES;
    float mean = sums[c] * invN;
    float ex2  = sums[128 + c] * invN;
    float mu = mean * gms[c];
    float var = ex2 - 2.f * mu * mean + mu * mu;
    float inv = rsqrtf(var + GN_EPS);
    float A = gw[c] * inv;
    AB[c] = A;
    AB[128 + c] = gb[c] - mu * A;
}

// ---------- kernel 10: affine + mish (in place on d_out) ----------
__global__ __launch_bounds__(256) void mish_kernel(float* __restrict__ out,
                                                   const float* __restrict__ AB) {
    int i = blockIdx.x * 256 + threadIdx.x;       // one float4 each; grid exact
    int c4 = (i << 2) & 127;
    float4 a  = *(const float4*)(AB + c4);
    float4 b  = *(const float4*)(AB + 128 + c4);
    float4 v  = *(float4*)(out + (size_t)i * 4);
    v.x = mishf(a.x * v.x + b.x);
    v.y = mishf(a.y * v.y + b.y);
    v.z = mishf(a.z * v.z + b.z);
    v.w = mishf(a.w * v.w + b.w);
    *(float4*)(out + (size_t)i * 4) = v;
}

// ---------- launch ----------
extern "C" void kernel_launch(void* const* d_in, const int* in_sizes, int n_in,
                              void* d_out, int out_size, void* d_ws, size_t ws_size,
                              hipStream_t stream) {
    (void)in_sizes; (void)n_in; (void)out_size; (void)ws_size;

    const float* x    = (const float*)d_in[0];
    const int*   ei   = (const int*)d_in[1];
    const float* Wq   = (const float*)d_in[2];
    const float* bq   = (const float*)d_in[3];
    const float* Wk   = (const float*)d_in[4];
    const float* bk   = (const float*)d_in[5];
    const float* Wv   = (const float*)d_in[6];
    const float* bv   = (const float*)d_in[7];
    const float* Wsk  = (const float*)d_in[8];
    const float* bsk  = (const float*)d_in[9];
    const float* gw   = (const float*)d_in[10];
    const float* gb   = (const float*)d_in[11];
    const float* gms  = (const float*)d_in[12];
    float* out = (float*)d_out;

    char* ws = (char*)d_ws;
    size_t o = 0;
    auto alloc = [&](size_t bytes) -> char* {
        char* p = ws + o;
        o += (bytes + 255) & ~(size_t)255;
        return p;
    };

    unsigned short* qb = (unsigned short*)alloc((size_t)N_NODES * D_OUT * 2);
    unsigned short* kb = (unsigned short*)alloc((size_t)N_NODES * D_OUT * 2);
    unsigned short* vb = (unsigned short*)alloc((size_t)N_NODES * D_OUT * 2);
    int* ssrc     = (int*)alloc((size_t)N_EDGES * 4);
    int* deg      = (int*)alloc((size_t)N_NODES * 4);
    int* off      = (int*)alloc((size_t)(N_NODES + 1) * 4);
    int* cursor   = (int*)alloc((size_t)N_NODES * 4);
    int* bsum     = (int*)alloc(512);
    float* sums   = (float*)alloc(1024);
    float* AB     = (float*)alloc(1024);
    unsigned short* Wt = (unsigned short*)alloc((size_t)512 * 256 * 2);
    float* bcat   = (float*)alloc(512 * 4);

    const int* srcp = ei;
    const int* dstp = ei + N_EDGES;

    hipMemsetAsync(deg, 0, (size_t)N_NODES * 4, stream);
    hipMemsetAsync(sums, 0, 256 * 4, stream);

    prep_w<<<512, 256, 0, stream>>>(Wq, Wk, Wv, Wsk, bq, bk, bv, bsk, Wt, bcat);
    gemm_mfma<<<(N_NODES + 63) / 64, 512, 0, stream>>>(x, Wt, bcat, qb, kb, vb, out);

    hist_kernel<<<(N_EDGES + 255) / 256, 256, 0, stream>>>(dstp, deg);
    scan1<<<98, 256, 0, stream>>>(deg, off, bsum);
    scan2<<<1, 128, 0, stream>>>(bsum);
    scan3<<<98, 256, 0, stream>>>(off, cursor, bsum);
    scatter_kernel<<<(N_EDGES + 255) / 256, 256, 0, stream>>>(srcp, dstp, cursor, ssrc);

    aggregate<<<N_NODES / 4, 256, 0, stream>>>(qb, kb, vb, off, cursor, ssrc, out);

    norm_reduce<<<512, 256, 0, stream>>>(out, sums);
    finalize<<<1, 128, 0, stream>>>(sums, gw, gb, gms, AB);
    mish_kernel<<<(N_NODES * D_OUT / 4) / 256, 256, 0, stream>>>(out, AB);
}